// Round 4
// baseline (1427.143 us; speedup 1.0000x reference)
//
#include <hip/hip_runtime.h>

// ---------------------------------------------------------------------------
// GATv2 3-layer GNN encoder. N=50000 nodes, E=800000 edges, dims 128.
// CSR build + degree-sort (once) -> per layer: [gemm xl, gemm xr,
// fused edge-score + segment-softmax + aggregate + bias + LN + ReLU].
// fused: 1 node per 128-thread block (2 waves x 64 dims), 4 edges in flight,
// edge indices batch-loaded and extracted via readlane (no per-edge dep loads).
// ---------------------------------------------------------------------------

__global__ __launch_bounds__(256) void hist_kernel(const int* __restrict__ dst,
                                                   int* __restrict__ deg, int nE) {
  int i = blockIdx.x * 256 + threadIdx.x;
  if (i < nE) atomicAdd(&deg[dst[i]], 1);
}

__global__ __launch_bounds__(1024) void scan_kernel(const int* __restrict__ deg,
                                                    int* __restrict__ rowptr, int n) {
  __shared__ int sdata[1024];
  int tid = threadIdx.x;
  if (tid == 0) rowptr[0] = 0;
  int carry = 0;
  for (int base = 0; base < n; base += 1024) {
    int i = base + tid;
    int v = (i < n) ? deg[i] : 0;
    sdata[tid] = v;
    __syncthreads();
    for (int ofs = 1; ofs < 1024; ofs <<= 1) {
      int t = (tid >= ofs) ? sdata[tid - ofs] : 0;
      __syncthreads();
      sdata[tid] += t;
      __syncthreads();
    }
    int inc = sdata[tid];
    int tot = sdata[1023];
    if (i < n) rowptr[i + 1] = carry + inc;
    carry += tot;
    __syncthreads();
  }
}

__global__ __launch_bounds__(256) void scatter_kernel(const int* __restrict__ dst,
                                                      const int* __restrict__ rowptr,
                                                      int* __restrict__ cnt,
                                                      int* __restrict__ eperm, int nE) {
  int i = blockIdx.x * 256 + threadIdx.x;
  if (i < nE) {
    int d = dst[i];
    int p = atomicAdd(&cnt[d], 1);
    eperm[rowptr[d] + p] = i;
  }
}

// --- degree sort: nodeorder = nodes sorted by degree descending (bucketed) ---
__global__ __launch_bounds__(256) void deg_hist(const int* __restrict__ rowptr,
                                                int* __restrict__ dh, int nN) {
  int i = blockIdx.x * 256 + threadIdx.x;
  if (i < nN) {
    int dg = min(rowptr[i + 1] - rowptr[i], 255);
    atomicAdd(&dh[dg], 1);
  }
}

__global__ __launch_bounds__(256) void deg_scan(const int* __restrict__ dh,
                                                int* __restrict__ dbase) {
  // descending-degree bases: dbase[b] = sum_{b' > b} dh[b']
  __shared__ int s[256];
  int t = threadIdx.x;
  s[t] = dh[t];
  __syncthreads();
  for (int ofs = 1; ofs < 256; ofs <<= 1) {
    int v = (t >= ofs) ? s[t - ofs] : 0;
    __syncthreads();
    s[t] += v;
    __syncthreads();
  }
  dbase[t] = s[255] - s[t];  // suffix (exclusive of own bucket)
}

__global__ __launch_bounds__(256) void deg_scatter(const int* __restrict__ rowptr,
                                                   const int* __restrict__ dbase,
                                                   int* __restrict__ dcnt,
                                                   int* __restrict__ nodeorder, int nN) {
  int i = blockIdx.x * 256 + threadIdx.x;
  if (i < nN) {
    int dg = min(rowptr[i + 1] - rowptr[i], 255);
    int p = atomicAdd(&dcnt[dg], 1);
    nodeorder[dbase[dg] + p] = i;
  }
}

// Y[r][c] = sum_k X[r][k]*W[k][c] + bias[c].  X: nrows x 128, W: 128 x 128.
__global__ __launch_bounds__(256) void node_gemm128(const float* __restrict__ X,
                                                    const float* __restrict__ W,
                                                    const float* __restrict__ bias,
                                                    float* __restrict__ Y, int nrows) {
  __shared__ float Xs[64][36];
  __shared__ float Ws[32][128];
  int tid = threadIdx.x;
  int r0 = blockIdx.x * 64;
  int col = tid & 127;
  int rh = tid >> 7;
  float acc[32];
#pragma unroll
  for (int i = 0; i < 32; ++i) acc[i] = 0.f;

  for (int k0 = 0; k0 < 128; k0 += 32) {
    __syncthreads();
#pragma unroll
    for (int j = tid; j < 512; j += 256) {
      int r = j >> 3, kk = (j & 7) << 2;
      float4 v = make_float4(0.f, 0.f, 0.f, 0.f);
      if (r0 + r < nrows) v = *(const float4*)&X[(size_t)(r0 + r) * 128 + k0 + kk];
      *(float4*)&Xs[r][kk] = v;
    }
#pragma unroll
    for (int j = tid; j < 1024; j += 256) {
      int k = j >> 5, nn = (j & 31) << 2;
      float4 v = *(const float4*)&W[(size_t)(k0 + k) * 128 + nn];
      *(float4*)&Ws[k][nn] = v;
    }
    __syncthreads();
#pragma unroll
    for (int k4 = 0; k4 < 32; k4 += 4) {
      float w0 = Ws[k4][col], w1 = Ws[k4 + 1][col];
      float w2 = Ws[k4 + 2][col], w3 = Ws[k4 + 3][col];
#pragma unroll
      for (int r = 0; r < 32; ++r) {
        float4 xv = *(const float4*)&Xs[rh * 32 + r][k4];
        acc[r] += xv.x * w0 + xv.y * w1 + xv.z * w2 + xv.w * w3;
      }
    }
  }
  float b = bias[col];
#pragma unroll
  for (int r = 0; r < 32; ++r) {
    int row = r0 + rh * 32 + r;
    if (row < nrows) Y[(size_t)row * 128 + col] = acc[r] + b;
  }
}

// Fused GATv2 layer. One node per 128-thread block; thread owns output dim
// c = wid*64+lane. 4 edges in flight. H=4: head = c>>5, score reduce is a
// 32-lane-group butterfly (stays in-wave). H=1: full 128-dim score -> in-wave
// 64-reduce + LDS cross-wave exchange (parity double-buffer, 1 barrier/group).
template <int H>
__global__ __launch_bounds__(128) void fused_gat(const float* __restrict__ xl,
                                                 const float* __restrict__ xr,
                                                 const float* __restrict__ ea,
                                                 const float* __restrict__ We,
                                                 const float* __restrict__ att,
                                                 const int* __restrict__ rowptr,
                                                 const int* __restrict__ eperm,
                                                 const int* __restrict__ src,
                                                 const int* __restrict__ nodeorder,
                                                 const float* __restrict__ bias,
                                                 const float* __restrict__ gam,
                                                 const float* __restrict__ bet,
                                                 float* __restrict__ out) {
  const int wid = threadIdx.x >> 6;
  const int lane = threadIdx.x & 63;
  const int c = wid * 64 + lane;
  const int n = __builtin_amdgcn_readfirstlane(nodeorder[blockIdx.x]);
  const int rb = __builtin_amdgcn_readfirstlane(rowptr[n]);
  const int re = __builtin_amdgcn_readfirstlane(rowptr[n + 1]);

  __shared__ float part[2][2][4];  // [parity][wid][edge]  (H==1 exchange)
  __shared__ float red[2][2];      // LN cross-wave sums

  float Wc[32];
#pragma unroll
  for (int k = 0; k < 32; ++k) Wc[k] = We[k * 128 + c];
  const float attc = att[c];
  const float xrc = xr[(size_t)n * 128 + c];

  float d = 0.f, acc = 0.f;
  int par = 0;

  for (int b0 = rb; b0 < re; b0 += 64) {
    const int cnt = min(64, re - b0);
    const int jj = b0 + lane;
    const int ev = (jj < re) ? eperm[jj] : 0;   // one coalesced load / 64 edges
    const int sv = (jj < re) ? src[ev] : 0;     // one gather / 64 edges

    for (int i = 0; i < cnt; i += 4) {
      // uniform (scalar) per-edge indices -- no memory on the critical path
      const int i0 = i, i1 = min(i + 1, cnt - 1), i2 = min(i + 2, cnt - 1),
                i3 = min(i + 3, cnt - 1);
      const int e0 = __builtin_amdgcn_readlane(ev, i0);
      const int e1 = __builtin_amdgcn_readlane(ev, i1);
      const int e2 = __builtin_amdgcn_readlane(ev, i2);
      const int e3 = __builtin_amdgcn_readlane(ev, i3);
      const int s0 = __builtin_amdgcn_readlane(sv, i0);
      const int s1 = __builtin_amdgcn_readlane(sv, i1);
      const int s2 = __builtin_amdgcn_readlane(sv, i2);
      const int s3 = __builtin_amdgcn_readlane(sv, i3);

      const float g0 = xl[(size_t)s0 * 128 + c];   // 256B coalesced gathers
      const float g1 = xl[(size_t)s1 * 128 + c];
      const float g2 = xl[(size_t)s2 * 128 + c];
      const float g3 = xl[(size_t)s3 * 128 + c];
      const float* r0p = ea + (size_t)e0 * 32;     // uniform -> s_load
      const float* r1p = ea + (size_t)e1 * 32;
      const float* r2p = ea + (size_t)e2 * 32;
      const float* r3p = ea + (size_t)e3 * 32;

      float m0 = g0 + xrc, m1 = g1 + xrc, m2 = g2 + xrc, m3 = g3 + xrc;
#pragma unroll
      for (int k = 0; k < 32; k += 4) {
        float4 q0 = *(const float4*)(r0p + k);
        float4 q1 = *(const float4*)(r1p + k);
        float4 q2 = *(const float4*)(r2p + k);
        float4 q3 = *(const float4*)(r3p + k);
        m0 += q0.x * Wc[k] + q0.y * Wc[k + 1] + q0.z * Wc[k + 2] + q0.w * Wc[k + 3];
        m1 += q1.x * Wc[k] + q1.y * Wc[k + 1] + q1.z * Wc[k + 2] + q1.w * Wc[k + 3];
        m2 += q2.x * Wc[k] + q2.y * Wc[k + 1] + q2.z * Wc[k + 2] + q2.w * Wc[k + 3];
        m3 += q3.x * Wc[k] + q3.y * Wc[k + 1] + q3.z * Wc[k + 2] + q3.w * Wc[k + 3];
      }
      float p0 = fmaxf(m0, 0.2f * m0) * attc;
      float p1 = fmaxf(m1, 0.2f * m1) * attc;
      float p2 = fmaxf(m2, 0.2f * m2) * attc;
      float p3 = fmaxf(m3, 0.2f * m3) * attc;

      if (H == 4) {
#pragma unroll
        for (int o = 16; o >= 1; o >>= 1) {   // 32-lane group == head
          p0 += __shfl_xor(p0, o);
          p1 += __shfl_xor(p1, o);
          p2 += __shfl_xor(p2, o);
          p3 += __shfl_xor(p3, o);
        }
      } else {
#pragma unroll
        for (int o = 32; o >= 1; o >>= 1) {   // full-wave partial (64 dims)
          p0 += __shfl_xor(p0, o);
          p1 += __shfl_xor(p1, o);
          p2 += __shfl_xor(p2, o);
          p3 += __shfl_xor(p3, o);
        }
        if (lane == 0) {
          part[par][wid][0] = p0;
          part[par][wid][1] = p1;
          part[par][wid][2] = p2;
          part[par][wid][3] = p3;
        }
        __syncthreads();
        p0 = part[par][0][0] + part[par][1][0];
        p1 = part[par][0][1] + part[par][1][1];
        p2 = part[par][0][2] + part[par][1][2];
        p3 = part[par][0][3] + part[par][1][3];
        par ^= 1;
      }

      float w0 = __expf(fminf(p0, 80.f));
      float w1 = __expf(fminf(p1, 80.f));
      float w2 = __expf(fminf(p2, 80.f));
      float w3 = __expf(fminf(p3, 80.f));
      if (i1 == i0) w1 = 0.f;   // masked padding (uniform conditions)
      if (i2 <= i1) w2 = 0.f;
      if (i3 <= i2) w3 = 0.f;
      d += w0 + w1 + w2 + w3;
      acc += w0 * g0 + w1 * g1 + w2 * g2 + w3 * g3;
    }
  }

  const float rd = (d > 0.f) ? 1.f / d : 0.f;
  const float y = acc * rd + bias[c];

  // LayerNorm over 128 dims: in-wave butterfly + LDS cross-wave combine
  float sm = y, sq = y * y;
#pragma unroll
  for (int o = 32; o >= 1; o >>= 1) {
    sm += __shfl_xor(sm, o);
    sq += __shfl_xor(sq, o);
  }
  if (lane == 0) {
    red[wid][0] = sm;
    red[wid][1] = sq;
  }
  __syncthreads();
  const float tots = red[0][0] + red[1][0];
  const float totq = red[0][1] + red[1][1];
  const float mu = tots * (1.f / 128.f);
  const float var = totq * (1.f / 128.f) - mu * mu;
  const float rstd = rsqrtf(var + 1e-5f);
  const float o0 = (y - mu) * rstd * gam[c] + bet[c];
  out[(size_t)n * 128 + c] = fmaxf(o0, 0.f);
}

extern "C" void kernel_launch(void* const* d_in, const int* in_sizes, int n_in,
                              void* d_out, int out_size, void* d_ws, size_t ws_size,
                              hipStream_t stream) {
  const float* x = (const float*)d_in[0];
  const float* ea = (const float*)d_in[1];
  const int* src = (const int*)d_in[2];
  const int* dst = (const int*)d_in[3];
  const int N = in_sizes[0] / 128;
  const int E = in_sizes[2];

  char* w = (char*)d_ws;
  auto alloc = [&](size_t bytes) {
    char* p = w;
    w += (bytes + 255) & ~(size_t)255;
    return p;
  };
  float* xl = (float*)alloc((size_t)N * 128 * 4);
  float* xr = (float*)alloc((size_t)N * 128 * 4);
  float* hA = (float*)alloc((size_t)N * 128 * 4);
  float* hB = (float*)alloc((size_t)N * 128 * 4);
  int* eperm = (int*)alloc((size_t)E * 4);
  int* rowptr = (int*)alloc((size_t)(N + 1) * 4);
  int* deg = (int*)alloc((size_t)N * 4);
  int* cnt = (int*)alloc((size_t)N * 4);
  int* nodeorder = (int*)alloc((size_t)N * 4);
  int* dh = (int*)alloc(256 * 4);
  int* dbase = (int*)alloc(256 * 4);
  int* dcnt = (int*)alloc(256 * 4);

  // CSR by dst + degree-descending node order (src/dst constant across layers)
  hipMemsetAsync(deg, 0, (size_t)N * 4, stream);
  hipMemsetAsync(cnt, 0, (size_t)N * 4, stream);
  hipMemsetAsync(dh, 0, 256 * 4, stream);
  hipMemsetAsync(dcnt, 0, 256 * 4, stream);
  hist_kernel<<<(E + 255) / 256, 256, 0, stream>>>(dst, deg, E);
  scan_kernel<<<1, 1024, 0, stream>>>(deg, rowptr, N);
  scatter_kernel<<<(E + 255) / 256, 256, 0, stream>>>(dst, rowptr, cnt, eperm, E);
  deg_hist<<<(N + 255) / 256, 256, 0, stream>>>(rowptr, dh, N);
  deg_scan<<<1, 256, 0, stream>>>(dh, dbase);
  deg_scatter<<<(N + 255) / 256, 256, 0, stream>>>(rowptr, dbase, dcnt, nodeorder, N);

  for (int l = 0; l < 3; ++l) {
    int bi = 4 + 9 * l;
    const float* Wl = (const float*)d_in[bi + 0];
    const float* bl = (const float*)d_in[bi + 1];
    const float* Wr = (const float*)d_in[bi + 2];
    const float* br = (const float*)d_in[bi + 3];
    const float* We = (const float*)d_in[bi + 4];
    const float* att = (const float*)d_in[bi + 5];
    const float* bo = (const float*)d_in[bi + 6];
    const float* gg = (const float*)d_in[bi + 7];
    const float* be = (const float*)d_in[bi + 8];
    const float* Xin = (l == 0) ? x : ((l == 1) ? hA : hB);
    float* Xout = (l == 2) ? (float*)d_out : ((l == 0) ? hA : hB);

    int gemmGrid = (N + 63) / 64;
    node_gemm128<<<gemmGrid, 256, 0, stream>>>(Xin, Wl, bl, xl, N);
    node_gemm128<<<gemmGrid, 256, 0, stream>>>(Xin, Wr, br, xr, N);
    if (l < 2) {
      fused_gat<4><<<N, 128, 0, stream>>>(xl, xr, ea, We, att, rowptr, eperm, src,
                                          nodeorder, bo, gg, be, Xout);
    } else {
      fused_gat<1><<<N, 128, 0, stream>>>(xl, xr, ea, We, att, rowptr, eperm, src,
                                          nodeorder, bo, gg, be, Xout);
    }
  }
}